// Round 7
// baseline (169.058 us; speedup 1.0000x reference)
//
#include <hip/hip_runtime.h>
#include <math.h>

#define BATCH 65536
#define LHIST 128
#define HFUT  32

__device__ __forceinline__ float softplusf(float x) {
    return fmaxf(x, 0.0f) + log1pf(expf(-fabsf(x)));   // jax.nn.softplus
}

// Named float4 staging (no arrays -> no scratch, proven r6: WRITE exactly ideal).
// NEW r7: __builtin_amdgcn_sched_barrier(0) after each prefetch block pins the
// 12 chunk loads ABOVE the 16-step compute. r6's VGPR=84 showed the scheduler
// sinks loads to first use, exposing ~900 cyc of memory latency per quad at
// 1 wave/SIMD (the ~110k stall cycles/wave = 68% idle).
__global__ __launch_bounds__(256, 1) void kalman_fwd(
    const float* __restrict__ v_hist,
    const float* __restrict__ dt_hist,
    const float* __restrict__ x_obs,
    const float* __restrict__ v_fut,
    const float* __restrict__ dt_fut,
    const float* __restrict__ theta,
    float* __restrict__ out)
{
    const int b = blockIdx.x * 256 + threadIdx.x;

    // ---- uniform parameter transforms ----
    const float alpha = 1.0f / (1.0f + expf(-theta[0]));
    const float c     = softplusf(theta[1]);
    const float kappa = softplusf(theta[2]);
    const float vc    = softplusf(theta[3]);       // VC_MIN = 0
    const float qx    = expf(theta[4]);
    const float qu    = expf(theta[5]);
    const float Rn    = expf(theta[6]);
    const float qs    = expf(theta[7]);
    const float p0xx  = expf(theta[8]);
    const float p0uu  = expf(theta[9]);
    const float a1    = softplusf(theta[10]);
    const float d1    = softplusf(theta[11]);
    const float d2    = softplusf(theta[12]);
    const float d3    = softplusf(theta[13]);
    const float b1    = theta[14];
    const float b2    = theta[15];
    const float beta  = theta[16];
    const float rho_m = tanhf(theta[17]);
    const float qm    = expf(theta[18]);
    const float p0mm  = expf(theta[19]);
    const float vc2   = vc * vc;
    const float qxs   = qs * qx;
    const float qus   = qs * qu;
    const float rm2   = rho_m * rho_m;
    const float nal2e = -alpha * 1.44269504088896340736f; // exp(-a*dt)=exp2(nal2e*dt)

    // ---- per-thread state ----
    float sx = 0.0f, su = 0.0f, sm = 0.0f;
    float p00 = p0xx, p01 = 0.0f, p02 = 0.0f, p11 = p0uu, p12 = 0.0f, p22 = p0mm;

    auto predict = [&](float v, float dv, float dt_raw) {
        float dt  = fmaxf(dt_raw, 1e-6f);
        float rho = __builtin_amdgcn_exp2f(nal2e * dt);
        float forcing = fmaxf(v * v - vc2, 0.0f);
        float cl = -a1 * su + b1 * v + b2 * dv
                 - d1 * su * su - d2 * su * fabsf(v) - d3 * su * fabsf(su);
        float kdt = kappa * dt;
        float x_p = sx + su * dt;
        float u_p = rho * su - kdt * sx + c * forcing * dt + cl * dt + beta * sm;
        float m_p = rho_m * sm;
        float f0 = p00 + dt * p01;
        float f1 = p01 + dt * p11;
        float f2 = p02 + dt * p12;
        float g0 = -kdt * p00 + rho * p01 + beta * p02;
        float g1 = -kdt * p01 + rho * p11 + beta * p12;
        float g2 = -kdt * p02 + rho * p12 + beta * p22;
        float n00 = f0 + dt * f1 + qxs * dt;
        float n01 = -kdt * f0 + rho * f1 + beta * f2;
        float n02 = rho_m * f2;
        float n11 = -kdt * g0 + rho * g1 + beta * g2 + qus * dt;
        float n12 = rho_m * g2;
        float n22 = rm2 * p22 + qm;
        sx = x_p; su = u_p; sm = m_p;
        p00 = n00; p01 = n01; p02 = n02; p11 = n11; p12 = n12; p22 = n22;
    };

    auto update = [&](float y) {
        float innov = y - sx;
        float S    = p00 + Rn;
        float Sinv = __builtin_amdgcn_rcpf(S);
        float K0 = p00 * Sinv, K1 = p01 * Sinv, K2 = p02 * Sinv;
        sx += K0 * innov; su += K1 * innov; sm += K2 * innov;
        float a = 1.0f - K0;
        float n00 = a * a * p00 + Rn * K0 * K0;
        float n01 = a * (p01 - K1 * p00) + Rn * K0 * K1;
        float n02 = a * (p02 - K2 * p00) + Rn * K0 * K2;
        float n11 = S * K1 * K1 - 2.0f * K1 * p01 + p11;
        float n12 = S * K1 * K2 - K2 * p01 - K1 * p02 + p12;
        float n22 = S * K2 * K2 - 2.0f * K2 * p02 + p22;
        p00 = n00; p01 = n01; p02 = n02; p11 = n11; p12 = n12; p22 = n22;
    };

    const float4* v4 = (const float4*)(v_hist  + (size_t)b * LHIST);
    const float4* d4 = (const float4*)(dt_hist + (size_t)b * LHIST);
    const float4* y4 = (const float4*)(x_obs   + (size_t)b * LHIST);

    // ---- history: 8 chunks x 16 steps; A/B double-buffered NAMED float4 regs ----
    // chunk k covers t = 16k-1 .. 16k+14 (chunk 0: t = 0..14)
    // step t: v[t], dv=v[t]-v[t-1] (0 at t=0), dt=dt_hist[t+1], y=x_obs[t+1]
    float4 AV0, AV1, AV2, AV3, AD0, AD1, AD2, AD3, AY0, AY1, AY2, AY3;
    float4 BV0, BV1, BV2, BV3, BD0, BD1, BD2, BD3, BY0, BY1, BY2, BY3;
    float vp1 = 0.0f, vp2 = 0.0f;   // v[16k-1], v[16k-2] bridges

#define LOAD_CHUNK(k, P) do {                                                    \
    P##V0 = v4[4*(k)+0]; P##V1 = v4[4*(k)+1];                                    \
    P##V2 = v4[4*(k)+2]; P##V3 = v4[4*(k)+3];                                    \
    P##D0 = d4[4*(k)+0]; P##D1 = d4[4*(k)+1];                                    \
    P##D2 = d4[4*(k)+2]; P##D3 = d4[4*(k)+3];                                    \
    P##Y0 = y4[4*(k)+0]; P##Y1 = y4[4*(k)+1];                                    \
    P##Y2 = y4[4*(k)+2]; P##Y3 = y4[4*(k)+3];                                    \
} while (0)

// scheduling fence: nothing crosses -> prefetch loads above stay above compute
#define PIN() __builtin_amdgcn_sched_barrier(0)

#define KSTEP(vc_, vpv_, dtn_, yn_) do { predict((vc_), (vc_) - (vpv_), (dtn_)); update(yn_); } while (0)

// 15 trailing steps shared by every chunk (t = 16k .. 16k+14)
#define CHUNK_TAIL(P) do {                                                       \
    KSTEP(P##V0.y, P##V0.x, P##D0.z, P##Y0.z);                                   \
    KSTEP(P##V0.z, P##V0.y, P##D0.w, P##Y0.w);                                   \
    KSTEP(P##V0.w, P##V0.z, P##D1.x, P##Y1.x);                                   \
    KSTEP(P##V1.x, P##V0.w, P##D1.y, P##Y1.y);                                   \
    KSTEP(P##V1.y, P##V1.x, P##D1.z, P##Y1.z);                                   \
    KSTEP(P##V1.z, P##V1.y, P##D1.w, P##Y1.w);                                   \
    KSTEP(P##V1.w, P##V1.z, P##D2.x, P##Y2.x);                                   \
    KSTEP(P##V2.x, P##V1.w, P##D2.y, P##Y2.y);                                   \
    KSTEP(P##V2.y, P##V2.x, P##D2.z, P##Y2.z);                                   \
    KSTEP(P##V2.z, P##V2.y, P##D2.w, P##Y2.w);                                   \
    KSTEP(P##V2.w, P##V2.z, P##D3.x, P##Y3.x);                                   \
    KSTEP(P##V3.x, P##V2.w, P##D3.y, P##Y3.y);                                   \
    KSTEP(P##V3.y, P##V3.x, P##D3.z, P##Y3.z);                                   \
    KSTEP(P##V3.z, P##V3.y, P##D3.w, P##Y3.w);                                   \
    vp2 = P##V3.z; vp1 = P##V3.w;                                                \
} while (0)

// regular chunk: bridge step t=16k-1, then t=16k, then tail
#define CHUNK(P) do {                                                            \
    predict(vp1, vp1 - vp2, P##D0.x);   update(P##Y0.x);                         \
    KSTEP(P##V0.x, vp1, P##D0.y, P##Y0.y);                                       \
    CHUNK_TAIL(P);                                                               \
} while (0)

    LOAD_CHUNK(0, A);
    LOAD_CHUNK(1, B);
    PIN();                              // both chunks' loads in flight now

    // chunk 0: t = 0..14 (no bridge; dv=0 at t=0)
    sx = AY0.x;                                   // s0.x = x_obs[b][0]
    predict(AV0.x, 0.0f, AD0.y); update(AY0.y);   // t = 0
    CHUNK_TAIL(A);

    #pragma unroll 1
    for (int k = 1; k <= 3; ++k) {
        LOAD_CHUNK(2 * k, A);           // prefetch chunk 2k
        PIN();                          // ...pinned above chunk 2k-1 compute
        CHUNK(B);                       // chunk 2k-1
        LOAD_CHUNK(2 * k + 1, B);       // prefetch chunk 2k+1
        PIN();                          // ...pinned above chunk 2k compute
        CHUNK(A);                       // chunk 2k
    }

    // ---- future inputs: prefetch pinned above final chunk compute ----
    const float4* vf4 = (const float4*)(v_fut  + (size_t)b * HFUT);
    const float4* df4 = (const float4*)(dt_fut + (size_t)b * HFUT);
    float4 VF0 = vf4[0], VF1 = vf4[1], VF2 = vf4[2], VF3 = vf4[3],
           VF4 = vf4[4], VF5 = vf4[5], VF6 = vf4[6], VF7 = vf4[7];
    float4 DF0 = df4[0], DF1 = df4[1], DF2 = df4[2], DF3 = df4[3],
           DF4 = df4[4], DF5 = df4[5], DF6 = df4[6], DF7 = df4[7];
    PIN();

    CHUNK(B);                           // chunk 7; vp1 = v_hist[b][127]

    // ---- future rollout: outputs into named float4 regs, then burst stores ----
    float4 OP0, OP1, OP2, OP3, OP4, OP5, OP6, OP7;
    float4 OV0, OV1, OV2, OV3, OV4, OV5, OV6, OV7;
    float4 OU0, OU1, OU2, OU3, OU4, OU5, OU6, OU7;
    float vp = vp1;

#define FUTQ(VF, DF, OP, OV, OU) do {                                            \
    predict(VF.x, VF.x - vp,   DF.x); OP.x = sx; OV.x = p00; OU.x = su;          \
    predict(VF.y, VF.y - VF.x, DF.y); OP.y = sx; OV.y = p00; OU.y = su;          \
    predict(VF.z, VF.z - VF.y, DF.z); OP.z = sx; OV.z = p00; OU.z = su;          \
    predict(VF.w, VF.w - VF.z, DF.w); OP.w = sx; OV.w = p00; OU.w = su;          \
    vp = VF.w;                                                                   \
} while (0)

    FUTQ(VF0, DF0, OP0, OV0, OU0);
    FUTQ(VF1, DF1, OP1, OV1, OU1);
    FUTQ(VF2, DF2, OP2, OV2, OU2);
    FUTQ(VF3, DF3, OP3, OV3, OU3);
    FUTQ(VF4, DF4, OP4, OV4, OU4);
    FUTQ(VF5, DF5, OP5, OV5, OU5);
    FUTQ(VF6, DF6, OP6, OV6, OU6);
    FUTQ(VF7, DF7, OP7, OV7, OU7);

    float4* xp = (float4*)(out + (size_t)b * HFUT);
    float4* xv = (float4*)(out + (size_t)BATCH * HFUT + (size_t)b * HFUT);
    float4* ue = (float4*)(out + 2 * (size_t)BATCH * HFUT + (size_t)b * HFUT);
    xp[0] = OP0; xp[1] = OP1; xp[2] = OP2; xp[3] = OP3;
    xp[4] = OP4; xp[5] = OP5; xp[6] = OP6; xp[7] = OP7;
    xv[0] = OV0; xv[1] = OV1; xv[2] = OV2; xv[3] = OV3;
    xv[4] = OV4; xv[5] = OV5; xv[6] = OV6; xv[7] = OV7;
    ue[0] = OU0; ue[1] = OU1; ue[2] = OU2; ue[3] = OU3;
    ue[4] = OU4; ue[5] = OU5; ue[6] = OU6; ue[7] = OU7;
}

extern "C" void kernel_launch(void* const* d_in, const int* in_sizes, int n_in,
                              void* d_out, int out_size, void* d_ws, size_t ws_size,
                              hipStream_t stream) {
    const float* v_hist  = (const float*)d_in[0];
    const float* dt_hist = (const float*)d_in[1];
    const float* x_obs   = (const float*)d_in[2];
    const float* v_fut   = (const float*)d_in[3];
    const float* dt_fut  = (const float*)d_in[4];
    const float* theta   = (const float*)d_in[5];
    float* out = (float*)d_out;

    dim3 grid(BATCH / 256), block(256);
    hipLaunchKernelGGL(kalman_fwd, grid, block, 0, stream,
                       v_hist, dt_hist, x_obs, v_fut, dt_fut, theta, out);
}

// Round 8
// 162.322 us; speedup vs baseline: 1.0415x; 1.0415x over previous
//
#include <hip/hip_runtime.h>
#include <math.h>

#define BATCH 65536
#define LHIST 128
#define HFUT  32

__device__ __forceinline__ float softplusf(float x) {
    return fmaxf(x, 0.0f) + log1pf(expf(-fabsf(x)));   // jax.nn.softplus
}

// r8: (1) standard-form Kalman update P' = P - K p0^T (algebraically == the
// reference's Joseph form; 13 ops vs ~30), (2) compact CH=8 rolled pair-loop
// (~9 KB body, L1I-resident) instead of 60 KB straight-line, (3) VMEM-only
// sched fence (mask 0x6: VALU/SALU may cross) to keep prefetch hoisted.
// Named float4 staging throughout (arrays+casts -> scratch, proven r2-r4).
__global__ __launch_bounds__(256, 1) void kalman_fwd(
    const float* __restrict__ v_hist,
    const float* __restrict__ dt_hist,
    const float* __restrict__ x_obs,
    const float* __restrict__ v_fut,
    const float* __restrict__ dt_fut,
    const float* __restrict__ theta,
    float* __restrict__ out)
{
    const int b = blockIdx.x * 256 + threadIdx.x;

    // ---- uniform parameter transforms ----
    const float alpha = 1.0f / (1.0f + expf(-theta[0]));
    const float c     = softplusf(theta[1]);
    const float kappa = softplusf(theta[2]);
    const float vc    = softplusf(theta[3]);       // VC_MIN = 0
    const float qx    = expf(theta[4]);
    const float qu    = expf(theta[5]);
    const float Rn    = expf(theta[6]);
    const float qs    = expf(theta[7]);
    const float p0xx  = expf(theta[8]);
    const float p0uu  = expf(theta[9]);
    const float a1    = softplusf(theta[10]);
    const float d1    = softplusf(theta[11]);
    const float d2    = softplusf(theta[12]);
    const float d3    = softplusf(theta[13]);
    const float b1    = theta[14];
    const float b2    = theta[15];
    const float beta  = theta[16];
    const float rho_m = tanhf(theta[17]);
    const float qm    = expf(theta[18]);
    const float p0mm  = expf(theta[19]);
    const float vc2   = vc * vc;
    const float qxs   = qs * qx;
    const float qus   = qs * qu;
    const float rm2   = rho_m * rho_m;
    const float nal2e = -alpha * 1.44269504088896340736f; // exp(-a*dt)=exp2(nal2e*dt)

    // ---- per-thread state ----
    float sx = 0.0f, su = 0.0f, sm = 0.0f;
    float p00 = p0xx, p01 = 0.0f, p02 = 0.0f, p11 = p0uu, p12 = 0.0f, p22 = p0mm;

    auto predict = [&](float v, float dv, float dt_raw) {
        float dt  = fmaxf(dt_raw, 1e-6f);
        float rho = __builtin_amdgcn_exp2f(nal2e * dt);
        float forcing = fmaxf(fmaf(v, v, -vc2), 0.0f);
        float cl = -a1 * su + b1 * v + b2 * dv
                 - d1 * su * su - d2 * su * fabsf(v) - d3 * su * fabsf(su);
        float kdt = kappa * dt;
        float x_p = fmaf(su, dt, sx);
        float u_p = fmaf(dt, fmaf(c, forcing, cl),
                         fmaf(-kdt, sx, fmaf(rho, su, beta * sm)));
        float m_p = rho_m * sm;
        // F = [[1,dt,0],[-kdt,rho,beta],[0,0,rho_m]];  P' = F P F^T + diag(q)
        float f0 = fmaf(dt, p01, p00);
        float f1 = fmaf(dt, p11, p01);
        float f2 = fmaf(dt, p12, p02);
        float g0 = fmaf(-kdt, p00, fmaf(rho, p01, beta * p02));
        float g1 = fmaf(-kdt, p01, fmaf(rho, p11, beta * p12));
        float g2 = fmaf(-kdt, p02, fmaf(rho, p12, beta * p22));
        float n00 = fmaf(dt, f1, f0) + qxs * dt;
        float n01 = fmaf(-kdt, f0, fmaf(rho, f1, beta * f2));
        float n02 = rho_m * f2;
        float n11 = fmaf(-kdt, g0, fmaf(rho, g1, beta * g2)) + qus * dt;
        float n12 = rho_m * g2;
        float n22 = fmaf(rm2, p22, qm);
        sx = x_p; su = u_p; sm = m_p;
        p00 = n00; p01 = n01; p02 = n02; p11 = n11; p12 = n12; p22 = n22;
    };

    // standard form P' = P - p0 p0^T / S  == reference Joseph form exactly
    // (expand (I-KH)P(I-KH)'+RKK': cross terms cancel). 13 ops vs ~30.
    auto update = [&](float y) {
        float innov = y - sx;
        float S    = p00 + Rn;
        float Sinv = __builtin_amdgcn_rcpf(S);
        float K0 = p00 * Sinv, K1 = p01 * Sinv, K2 = p02 * Sinv;
        sx = fmaf(K0, innov, sx);
        su = fmaf(K1, innov, su);
        sm = fmaf(K2, innov, sm);
        float n11 = fmaf(-K1, p01, p11);
        float n12 = fmaf(-K1, p02, p12);
        float n22 = fmaf(-K2, p02, p22);
        float a = 1.0f - K0;
        p00 *= a; p01 *= a; p02 *= a;
        p11 = n11; p12 = n12; p22 = n22;
    };

    const float4* v4 = (const float4*)(v_hist  + (size_t)b * LHIST);
    const float4* d4 = (const float4*)(dt_hist + (size_t)b * LHIST);
    const float4* y4 = (const float4*)(x_obs   + (size_t)b * LHIST);

    // ---- history: 16 chunks x 8 steps; A/B double-buffered named float4 ----
    // chunk k covers t = 8k-1 .. 8k+6 (chunk 0: t = 0..6)
    // step t: v[t], dv=v[t]-v[t-1] (0 at t=0), dt=dt_hist[t+1], y=x_obs[t+1]
    float4 AV0, AV1, AD0, AD1, AY0, AY1;
    float4 BV0, BV1, BD0, BD1, BY0, BY1;
    float vp1 = 0.0f, vp2 = 0.0f;   // v[8k-1], v[8k-2] bridges

#define LOAD8(k, P) do {                                                        \
    P##V0 = v4[2*(k)];   P##V1 = v4[2*(k)+1];                                   \
    P##D0 = d4[2*(k)];   P##D1 = d4[2*(k)+1];                                   \
    P##Y0 = y4[2*(k)];   P##Y1 = y4[2*(k)+1];                                   \
} while (0)

// VMEM may not cross; VALU(0x2)/SALU(0x4) may -> loads stay hoisted, ALU free
#define PINV() __builtin_amdgcn_sched_barrier(0x0006)

#define KSTEP(vc_, vpv_, dtn_, yn_) do { predict((vc_), (vc_) - (vpv_), (dtn_)); update(yn_); } while (0)

// 6 trailing steps (t = 8k+1 .. 8k+6) + bridge bookkeeping
#define CHUNK8_TAIL(P) do {                                                     \
    KSTEP(P##V0.y, P##V0.x, P##D0.z, P##Y0.z);                                  \
    KSTEP(P##V0.z, P##V0.y, P##D0.w, P##Y0.w);                                  \
    KSTEP(P##V0.w, P##V0.z, P##D1.x, P##Y1.x);                                  \
    KSTEP(P##V1.x, P##V0.w, P##D1.y, P##Y1.y);                                  \
    KSTEP(P##V1.y, P##V1.x, P##D1.z, P##Y1.z);                                  \
    KSTEP(P##V1.z, P##V1.y, P##D1.w, P##Y1.w);                                  \
    vp2 = P##V1.z; vp1 = P##V1.w;                                               \
} while (0)

#define CHUNK8(P) do {                                                          \
    predict(vp1, vp1 - vp2, P##D0.x);  update(P##Y0.x);   /* t = 8k-1 */        \
    KSTEP(P##V0.x, vp1, P##D0.y, P##Y0.y);                /* t = 8k   */        \
    CHUNK8_TAIL(P);                                                             \
} while (0)

    LOAD8(0, A);
    LOAD8(1, B);
    PINV();

    // chunk 0: t = 0..6 (no bridge; dv=0 at t=0)
    sx = AY0.x;                                   // s0.x = x_obs[b][0]
    predict(AV0.x, 0.0f, AD0.y); update(AY0.y);   // t = 0
    CHUNK8_TAIL(A);

    // chunks 1..14 in pairs; chunk i in B, i+1 loading into A, etc.
    #pragma unroll 1
    for (int i = 1; i <= 13; i += 2) {
        LOAD8(i + 1, A);  PINV();       // in flight across chunk i compute
        CHUNK8(B);                      // chunk i
        LOAD8(i + 2, B);  PINV();       // in flight across chunk i+1 compute
        CHUNK8(A);                      // chunk i+1
    }
    // loop did chunks 1..14; B holds chunk 15

    // ---- future inputs: prefetch above final chunk compute ----
    const float4* vf4 = (const float4*)(v_fut  + (size_t)b * HFUT);
    const float4* df4 = (const float4*)(dt_fut + (size_t)b * HFUT);
    float4 VF0 = vf4[0], VF1 = vf4[1], VF2 = vf4[2], VF3 = vf4[3],
           VF4 = vf4[4], VF5 = vf4[5], VF6 = vf4[6], VF7 = vf4[7];
    float4 DF0 = df4[0], DF1 = df4[1], DF2 = df4[2], DF3 = df4[3],
           DF4 = df4[4], DF5 = df4[5], DF6 = df4[6], DF7 = df4[7];
    PINV();

    CHUNK8(B);                          // chunk 15; vp1 = v_hist[b][127]

    // ---- future rollout: outputs into named float4 regs, then burst stores ----
    float4 OP0, OP1, OP2, OP3, OP4, OP5, OP6, OP7;
    float4 OV0, OV1, OV2, OV3, OV4, OV5, OV6, OV7;
    float4 OU0, OU1, OU2, OU3, OU4, OU5, OU6, OU7;
    float vp = vp1;

#define FUTQ(VF, DF, OP, OV, OU) do {                                           \
    predict(VF.x, VF.x - vp,   DF.x); OP.x = sx; OV.x = p00; OU.x = su;         \
    predict(VF.y, VF.y - VF.x, DF.y); OP.y = sx; OV.y = p00; OU.y = su;         \
    predict(VF.z, VF.z - VF.y, DF.z); OP.z = sx; OV.z = p00; OU.z = su;         \
    predict(VF.w, VF.w - VF.z, DF.w); OP.w = sx; OV.w = p00; OU.w = su;         \
    vp = VF.w;                                                                  \
} while (0)

    FUTQ(VF0, DF0, OP0, OV0, OU0);
    FUTQ(VF1, DF1, OP1, OV1, OU1);
    FUTQ(VF2, DF2, OP2, OV2, OU2);
    FUTQ(VF3, DF3, OP3, OV3, OU3);
    FUTQ(VF4, DF4, OP4, OV4, OU4);
    FUTQ(VF5, DF5, OP5, OV5, OU5);
    FUTQ(VF6, DF6, OP6, OV6, OU6);
    FUTQ(VF7, DF7, OP7, OV7, OU7);

    float4* xp = (float4*)(out + (size_t)b * HFUT);
    float4* xv = (float4*)(out + (size_t)BATCH * HFUT + (size_t)b * HFUT);
    float4* ue = (float4*)(out + 2 * (size_t)BATCH * HFUT + (size_t)b * HFUT);
    xp[0] = OP0; xp[1] = OP1; xp[2] = OP2; xp[3] = OP3;
    xp[4] = OP4; xp[5] = OP5; xp[6] = OP6; xp[7] = OP7;
    xv[0] = OV0; xv[1] = OV1; xv[2] = OV2; xv[3] = OV3;
    xv[4] = OV4; xv[5] = OV5; xv[6] = OV6; xv[7] = OV7;
    ue[0] = OU0; ue[1] = OU1; ue[2] = OU2; ue[3] = OU3;
    ue[4] = OU4; ue[5] = OU5; ue[6] = OU6; ue[7] = OU7;
}

extern "C" void kernel_launch(void* const* d_in, const int* in_sizes, int n_in,
                              void* d_out, int out_size, void* d_ws, size_t ws_size,
                              hipStream_t stream) {
    const float* v_hist  = (const float*)d_in[0];
    const float* dt_hist = (const float*)d_in[1];
    const float* x_obs   = (const float*)d_in[2];
    const float* v_fut   = (const float*)d_in[3];
    const float* dt_fut  = (const float*)d_in[4];
    const float* theta   = (const float*)d_in[5];
    float* out = (float*)d_out;

    dim3 grid(BATCH / 256), block(256);
    hipLaunchKernelGGL(kalman_fwd, grid, block, 0, stream,
                       v_hist, dt_hist, x_obs, v_fut, dt_fut, theta, out);
}